// Round 1
// baseline (124.296 us; speedup 1.0000x reference)
//
#include <hip/hip_runtime.h>

// Minimax Conv2D: out[b,o,h,w] = min_p( max_q( x_patch[conn[o,9p+q... ]] - w1[o,t] ) - w2[o,p] )
// x: (16,64,64,64) f32, replicate pad 1 on H,W; patch index = c*9 + kh*3 + kw.

#define IN_C  64
#define OUT_C 128
#define BB    16
#define HH    64
#define WW    64
#define TH    4            // tile rows
#define TW    16           // tile cols
#define LR    (TH + 2)     // 6 LDS rows (with halo)
#define LC    (TW + 2)     // 18 LDS cols (with halo)
#define CH_STRIDE (LR * LC) // 108 floats per channel

__global__ __launch_bounds__(256, 4)
void minimax_conv_kernel(const float* __restrict__ x,
                         const float* __restrict__ w1,
                         const float* __restrict__ w2,
                         const int*   __restrict__ conn,
                         float*       __restrict__ out) {
    __shared__ float xs[IN_C * CH_STRIDE];   // 64*108*4 = 27648 B

    const int tid = threadIdx.x;
    const int wt  = blockIdx.x;   // 0..3   (W tiles)
    const int ht  = blockIdx.y;   // 0..15  (H tiles)
    const int b   = blockIdx.z;   // 0..15  (batch)
    const int h0  = ht * TH;
    const int w0  = wt * TW;

    // ---- stage x tile (all 64 channels, replicate-clamped halo) ----
    const float* xb = x + (size_t)b * IN_C * HH * WW;
    for (int i = tid; i < IN_C * CH_STRIDE; i += 256) {
        int c  = i / CH_STRIDE;
        int rm = i - c * CH_STRIDE;
        int rr = rm / LC;
        int cc = rm - rr * LC;
        int gh = h0 + rr - 1; gh = gh < 0 ? 0 : (gh > HH - 1 ? HH - 1 : gh);
        int gw = w0 + cc - 1; gw = gw < 0 ? 0 : (gw > WW - 1 ? WW - 1 : gw);
        xs[i] = xb[(c * HH + gh) * WW + gw];
    }
    __syncthreads();

    // ---- compute: each wave owns 32 output channels, 1 pixel per lane ----
    const int lane = tid & 63;
    // wave id made provably wave-uniform so conn/w1/w2 reads scalarize (s_load)
    const int wid  = __builtin_amdgcn_readfirstlane(tid >> 6);
    const int r    = lane >> 4;    // 0..3
    const int cc   = lane & 15;    // 0..15
    const int base = r * LC + cc;  // pixel origin in padded LDS tile

    float* op = out + (((size_t)b * OUT_C) * HH + (h0 + r)) * WW + (w0 + cc);

    for (int oo = 0; oo < 32; ++oo) {
        const int o = wid * 32 + oo;
        const int*   cp  = conn + o * 9;
        const float* w1p = w1   + o * 9;
        const float* w2p = w2   + o * 3;

        float mi = 0.0f;
        #pragma unroll
        for (int p = 0; p < 3; ++p) {
            float ma = 0.0f;
            #pragma unroll
            for (int q = 0; q < 3; ++q) {
                const int t   = p * 3 + q;
                const int idx = cp[t];          // 0..575, wave-uniform
                const int c   = idx / 9;
                const int k   = idx - c * 9;
                const int kh  = k / 3;
                const int kw  = k - kh * 3;
                const int delta = c * CH_STRIDE + kh * LC + kw;  // wave-uniform
                const float d = xs[base + delta] - w1p[t];
                ma = (q == 0) ? d : fmaxf(ma, d);
            }
            const float v = ma - w2p[p];
            mi = (p == 0) ? v : fminf(mi, v);
        }
        op[(size_t)o * (HH * WW)] = mi;
    }
}

extern "C" void kernel_launch(void* const* d_in, const int* in_sizes, int n_in,
                              void* d_out, int out_size, void* d_ws, size_t ws_size,
                              hipStream_t stream) {
    const float* x    = (const float*)d_in[0];
    const float* w1   = (const float*)d_in[1];
    const float* w2   = (const float*)d_in[2];
    const int*   conn = (const int*)d_in[3];
    float*       out  = (float*)d_out;

    dim3 grid(WW / TW, HH / TH, BB);   // 4 x 16 x 16 = 1024 blocks
    minimax_conv_kernel<<<grid, 256, 0, stream>>>(x, w1, w2, conn, out);
}

// Round 2
// 123.202 us; speedup vs baseline: 1.0089x; 1.0089x over previous
//
#include <hip/hip_runtime.h>

// Minimax Conv2D: out[b,o,h,w] = min_p( max_q( patch[conn[o,3p+q]] - w1[o,3p+q] ) - w2[o,p] )
// x: (16,64,64,64) f32, replicate pad 1 on H,W; patch index = c*9 + kh*3 + kw.

#define IN_C  64
#define OUT_C 128
#define BB    16
#define HH    64
#define WW    64
#define TH    4            // tile rows
#define TW    16           // tile cols
#define LR    (TH + 2)     // 6 rows incl. halo
#define LCV   (TW + 2)     // 18 valid cols incl. halo
#define LC    24           // padded row stride: rows map to disjoint 2-way bank halves
#define CH_STRIDE (LR * LC) // 144 floats per channel
#define UNROLL 4

__global__ __launch_bounds__(256, 4)
void minimax_conv_kernel(const float* __restrict__ x,
                         const float* __restrict__ w1,
                         const float* __restrict__ w2,
                         const int*   __restrict__ conn,
                         float*       __restrict__ out) {
    __shared__ float xs[IN_C * CH_STRIDE];   // 64*144*4 = 36864 B

    const int tid = threadIdx.x;
    const int wt  = blockIdx.x;   // 0..3   (W tiles)
    const int ht  = blockIdx.y;   // 0..15  (H tiles)
    const int b   = blockIdx.z;   // 0..15  (batch)
    const int h0  = ht * TH;
    const int w0  = wt * TW;

    // ---- stage x tile (all 64 channels, replicate-clamped halo) ----
    const float* xb = x + (size_t)b * IN_C * HH * WW;
    for (int i = tid; i < IN_C * LR * LCV; i += 256) {
        int c  = i / (LR * LCV);
        int rm = i - c * (LR * LCV);
        int rr = rm / LCV;
        int cc = rm - rr * LCV;
        int gh = h0 + rr - 1; gh = gh < 0 ? 0 : (gh > HH - 1 ? HH - 1 : gh);
        int gw = w0 + cc - 1; gw = gw < 0 ? 0 : (gw > WW - 1 ? WW - 1 : gw);
        xs[c * CH_STRIDE + rr * LC + cc] = xb[(c * HH + gh) * WW + gw];
    }
    __syncthreads();

    // ---- compute: each wave owns 32 output channels, 1 pixel per lane ----
    const int lane = tid & 63;
    const int wid  = __builtin_amdgcn_readfirstlane(tid >> 6);  // uniform -> conn/w1/w2 scalarize
    const int r    = lane >> 4;    // 0..3
    const int cc   = lane & 15;    // 0..15
    const int base = r * LC + cc;  // pixel origin in padded LDS tile

    // output base for this wave's first channel
    float* op = out + ((((size_t)b * OUT_C + wid * 32) * HH) + (h0 + r)) * WW + (w0 + cc);

    for (int oo = 0; oo < 32; oo += UNROLL) {
        // ---- issue all 36 gathers first: 4 independent chains, max MLP ----
        float v[UNROLL][9];
        #pragma unroll
        for (int u = 0; u < UNROLL; ++u) {
            const int o = wid * 32 + oo + u;
            const int* cp = conn + o * 9;
            #pragma unroll
            for (int t = 0; t < 9; ++t) {
                const int idx = cp[t];              // wave-uniform (s_load)
                const int c   = idx / 9;
                const int k   = idx - c * 9;
                const int kh  = k / 3;
                const int kw  = k - kh * 3;
                v[u][t] = xs[base + c * CH_STRIDE + kh * LC + kw];
            }
        }
        // ---- reduce and store ----
        #pragma unroll
        for (int u = 0; u < UNROLL; ++u) {
            const int o = wid * 32 + oo + u;
            const float* w1p = w1 + o * 9;
            const float* w2p = w2 + o * 3;
            float mi = 0.0f;
            #pragma unroll
            for (int p = 0; p < 3; ++p) {
                float ma = v[u][p * 3 + 0] - w1p[p * 3 + 0];
                ma = fmaxf(ma, v[u][p * 3 + 1] - w1p[p * 3 + 1]);
                ma = fmaxf(ma, v[u][p * 3 + 2] - w1p[p * 3 + 2]);
                const float t = ma - w2p[p];
                mi = (p == 0) ? t : fminf(mi, t);
            }
            op[(size_t)(oo + u) * (HH * WW)] = mi;
        }
    }
}

extern "C" void kernel_launch(void* const* d_in, const int* in_sizes, int n_in,
                              void* d_out, int out_size, void* d_ws, size_t ws_size,
                              hipStream_t stream) {
    const float* x    = (const float*)d_in[0];
    const float* w1   = (const float*)d_in[1];
    const float* w2   = (const float*)d_in[2];
    const int*   conn = (const int*)d_in[3];
    float*       out  = (float*)d_out;

    dim3 grid(WW / TW, HH / TH, BB);   // 4 x 16 x 16 = 1024 blocks
    minimax_conv_kernel<<<grid, 256, 0, stream>>>(x, w1, w2, conn, out);
}

// Round 3
// 121.079 us; speedup vs baseline: 1.0266x; 1.0175x over previous
//
#include <hip/hip_runtime.h>

// Minimax Conv2D: out[b,o,h,w] = min_p( max_q( patch[conn[o,3p+q]] - w1[o,3p+q] ) - w2[o,p] )
// x: (16,64,64,64) f32, replicate pad 1 on H,W; patch index = c*9 + kh*3 + kw.
//
// R3 structure: 512-thread blocks (8 waves), LDS tile 64ch x 6 x 18 (27.6 KB, stride 18)
// -> 4 blocks/CU x 8 waves = 32 waves/CU (100% occupancy), VGPR forced <=64.

#define IN_C  64
#define OUT_C 128
#define BB    16
#define HH    64
#define WW    64
#define TH    4             // tile rows
#define TW    16            // tile cols
#define LR    (TH + 2)      // 6 rows incl. halo
#define LC    (TW + 2)      // 18 cols incl. halo (also LDS row stride; ~free 2-way banks)
#define CH_STRIDE (LR * LC) // 108 floats per channel
#define NTHR  512
#define CH_PER_WAVE 16      // 8 waves x 16 = 128 output channels
#define UNROLL 2

__global__ __launch_bounds__(NTHR, 8)
void minimax_conv_kernel(const float* __restrict__ x,
                         const float* __restrict__ w1,
                         const float* __restrict__ w2,
                         const int*   __restrict__ conn,
                         float*       __restrict__ out) {
    __shared__ float xs[IN_C * CH_STRIDE];   // 64*108*4 = 27648 B

    const int tid = threadIdx.x;
    const int wt  = blockIdx.x;   // 0..3   (W tiles)
    const int ht  = blockIdx.y;   // 0..15  (H tiles)
    const int b   = blockIdx.z;   // 0..15  (batch)
    const int h0  = ht * TH;
    const int w0  = wt * TW;

    // ---- stage x tile (all 64 channels, replicate-clamped halo) ----
    const float* xb = x + (size_t)b * IN_C * HH * WW;
    for (int i = tid; i < IN_C * CH_STRIDE; i += NTHR) {
        int c  = i / CH_STRIDE;
        int rm = i - c * CH_STRIDE;
        int rr = rm / LC;
        int cc = rm - rr * LC;
        int gh = h0 + rr - 1; gh = gh < 0 ? 0 : (gh > HH - 1 ? HH - 1 : gh);
        int gw = w0 + cc - 1; gw = gw < 0 ? 0 : (gw > WW - 1 ? WW - 1 : gw);
        xs[i] = xb[(c * HH + gh) * WW + gw];
    }
    __syncthreads();

    // ---- compute: each wave owns 16 output channels, 1 pixel per lane ----
    const int lane = tid & 63;
    const int wid  = __builtin_amdgcn_readfirstlane(tid >> 6);  // 0..7, uniform
    const int r    = lane >> 4;    // 0..3
    const int cc   = lane & 15;    // 0..15
    const int base = r * LC + cc;  // pixel origin in LDS tile

    // output base for this wave's first channel
    float* op = out + ((((size_t)b * OUT_C + wid * CH_PER_WAVE) * HH) + (h0 + r)) * WW + (w0 + cc);

    for (int oo = 0; oo < CH_PER_WAVE; oo += UNROLL) {
        // ---- issue all gathers for UNROLL channels first ----
        float v[UNROLL][9];
        #pragma unroll
        for (int u = 0; u < UNROLL; ++u) {
            const int o = wid * CH_PER_WAVE + oo + u;
            const int* cp = conn + o * 9;
            #pragma unroll
            for (int t = 0; t < 9; ++t) {
                const int idx = cp[t];              // wave-uniform (s_load)
                const int c   = idx / 9;
                const int k   = idx - c * 9;
                const int kh  = k / 3;
                const int kw  = k - kh * 3;
                v[u][t] = xs[base + c * CH_STRIDE + kh * LC + kw];
            }
        }
        // ---- reduce and store ----
        #pragma unroll
        for (int u = 0; u < UNROLL; ++u) {
            const int o = wid * CH_PER_WAVE + oo + u;
            const float* w1p = w1 + o * 9;
            const float* w2p = w2 + o * 3;
            float mi = 0.0f;
            #pragma unroll
            for (int p = 0; p < 3; ++p) {
                float ma = v[u][p * 3 + 0] - w1p[p * 3 + 0];
                ma = fmaxf(ma, v[u][p * 3 + 1] - w1p[p * 3 + 1]);
                ma = fmaxf(ma, v[u][p * 3 + 2] - w1p[p * 3 + 2]);
                const float t = ma - w2p[p];
                mi = (p == 0) ? t : fminf(mi, t);
            }
            op[(size_t)(oo + u) * (HH * WW)] = mi;
        }
    }
}

extern "C" void kernel_launch(void* const* d_in, const int* in_sizes, int n_in,
                              void* d_out, int out_size, void* d_ws, size_t ws_size,
                              hipStream_t stream) {
    const float* x    = (const float*)d_in[0];
    const float* w1   = (const float*)d_in[1];
    const float* w2   = (const float*)d_in[2];
    const int*   conn = (const int*)d_in[3];
    float*       out  = (float*)d_out;

    dim3 grid(WW / TW, HH / TH, BB);   // 4 x 16 x 16 = 1024 blocks
    minimax_conv_kernel<<<grid, NTHR, 0, stream>>>(x, w1, w2, conn, out);
}

// Round 6
// 101.009 us; speedup vs baseline: 1.2305x; 1.1987x over previous
//
#include <hip/hip_runtime.h>

// Minimax Conv2D: out[b,o,h,w] = min_p( max_q( patch[conn[o,3p+q]] - w1[o,3p+q] ) - w2[o,p] )
// x: (16,64,64,64) f32, replicate pad 1 on H,W; patch index = c*9 + kh*3 + kw.
//
// R4 (2nd resubmit after broker timeouts): kernel A precomputes conn -> LDS-dword-delta
// table in d_ws (kills per-block SALU index math; hot loop reads it via wave-uniform
// s_load). Kernel B: 4x32 pixel tile, 2 px/lane via ds_read2-mergeable paired reads,
// LDS row stride 40 (2-way banks = free on wave64).

#define IN_C  64
#define OUT_C 128
#define BB    16
#define HH    64
#define WW    64
#define TH    4              // tile rows
#define TW    32             // tile cols
#define LR    (TH + 2)       // 6 rows incl. halo
#define LCV   (TW + 2)       // 34 valid cols incl. halo
#define LC    40             // padded row stride (banks: S,S+8,S+16,S+24 -> free 2-way)
#define CH_STRIDE (LR * LC)  // 240 floats per channel
#define NTHR  512
#define CH_PER_WAVE 16       // 8 waves x 16 = 128 output channels
#define UNROLL 4
#define NTAB  (OUT_C * 9)    // 1152

__global__ void build_delta_table(const int* __restrict__ conn, int* __restrict__ dtab) {
    int i = blockIdx.x * 256 + threadIdx.x;
    if (i < NTAB) {
        int idx = conn[i];             // 0..575  (= c*9 + kh*3 + kw)
        int c   = idx / 9;
        int k   = idx - 9 * c;
        int kh  = k / 3;
        int kw  = k - 3 * kh;
        dtab[i] = c * CH_STRIDE + kh * LC + kw;   // final LDS dword offset
    }
}

__global__ __launch_bounds__(NTHR, 4)   // 4 waves/SIMD -> 2 blocks/CU, VGPR <= 128
void minimax_conv_kernel(const float* __restrict__ x,
                         const float* __restrict__ w1,
                         const float* __restrict__ w2,
                         const int*   __restrict__ dtab,
                         float*       __restrict__ out) {
    __shared__ float xs[IN_C * CH_STRIDE];   // 64*240*4 = 61440 B

    const int tid = threadIdx.x;
    const int wt  = blockIdx.x;   // 0..1   (W tiles)
    const int ht  = blockIdx.y;   // 0..15  (H tiles)
    const int b   = blockIdx.z;   // 0..15  (batch)
    const int h0  = ht * TH;
    const int w0  = wt * TW;

    // ---- stage x tile (all 64 channels, replicate-clamped halo), valid cols only ----
    const float* xb = x + (size_t)b * IN_C * HH * WW;
    for (int i = tid; i < IN_C * LR * LCV; i += NTHR) {
        int c  = i / (LR * LCV);
        int rm = i - c * (LR * LCV);
        int rr = rm / LCV;
        int cc = rm - rr * LCV;
        int gh = h0 + rr - 1; gh = gh < 0 ? 0 : (gh > HH - 1 ? HH - 1 : gh);
        int gw = w0 + cc - 1; gw = gw < 0 ? 0 : (gw > WW - 1 ? WW - 1 : gw);
        xs[c * CH_STRIDE + rr * LC + cc] = xb[(c * HH + gh) * WW + gw];
    }
    __syncthreads();

    // ---- compute: wave owns 16 channels; lane owns pixels (r,cc) and (r,cc+16) ----
    const int lane = tid & 63;
    const int wid  = __builtin_amdgcn_readfirstlane(tid >> 6);  // 0..7, uniform
    const int r    = lane >> 4;    // 0..3
    const int cc   = lane & 15;    // 0..15
    const int base = r * LC + cc;  // pixel origin (dwords) in LDS tile

    float* op = out + ((((size_t)b * OUT_C + wid * CH_PER_WAVE) * HH) + (h0 + r)) * WW + (w0 + cc);

    for (int oo = 0; oo < CH_PER_WAVE; oo += UNROLL) {
        // ---- issue all gathers first: UNROLL channels x 9 taps x 2 pixels ----
        float v[UNROLL][9][2];
        #pragma unroll
        for (int u = 0; u < UNROLL; ++u) {
            const int o = wid * CH_PER_WAVE + oo + u;
            const int* dp = dtab + o * 9;
            #pragma unroll
            for (int t = 0; t < 9; ++t) {
                const int d = dp[t];               // wave-uniform s_load, zero SALU math
                v[u][t][0] = xs[base + d];         // pair -> ds_read2_b32 offset0:0
                v[u][t][1] = xs[base + d + 16];    //                     offset1:16
            }
        }
        // ---- reduce and store ----
        #pragma unroll
        for (int u = 0; u < UNROLL; ++u) {
            const int o = wid * CH_PER_WAVE + oo + u;
            const float* w1p = w1 + o * 9;
            const float* w2p = w2 + o * 3;
            #pragma unroll
            for (int px = 0; px < 2; ++px) {
                float mi = 0.0f;
                #pragma unroll
                for (int p = 0; p < 3; ++p) {
                    float ma = v[u][p * 3 + 0][px] - w1p[p * 3 + 0];
                    ma = fmaxf(ma, v[u][p * 3 + 1][px] - w1p[p * 3 + 1]);
                    ma = fmaxf(ma, v[u][p * 3 + 2][px] - w1p[p * 3 + 2]);
                    const float t = ma - w2p[p];
                    mi = (p == 0) ? t : fminf(mi, t);
                }
                op[(size_t)(oo + u) * (HH * WW) + px * 16] = mi;
            }
        }
    }
}

extern "C" void kernel_launch(void* const* d_in, const int* in_sizes, int n_in,
                              void* d_out, int out_size, void* d_ws, size_t ws_size,
                              hipStream_t stream) {
    const float* x    = (const float*)d_in[0];
    const float* w1   = (const float*)d_in[1];
    const float* w2   = (const float*)d_in[2];
    const int*   conn = (const int*)d_in[3];
    float*       out  = (float*)d_out;
    int*         dtab = (int*)d_ws;   // 1152 * 4 B scratch

    build_delta_table<<<(NTAB + 255) / 256, 256, 0, stream>>>(conn, dtab);

    dim3 grid(WW / TW, HH / TH, BB);   // 2 x 16 x 16 = 512 blocks
    minimax_conv_kernel<<<grid, NTHR, 0, stream>>>(x, w1, w2, dtab, out);
}

// Round 7
// 97.282 us; speedup vs baseline: 1.2777x; 1.0383x over previous
//
#include <hip/hip_runtime.h>

// Minimax Conv2D: out[b,o,h,w] = min_p( max_q( patch[conn[o,3p+q]] - w1[o,3p+q] ) - w2[o,p] )
// x: (16,64,64,64) f32, replicate pad 1 on H,W; patch index = c*9 + kh*3 + kw.
//
// R7: lane = OUTPUT CHANNEL. All per-channel constants (gather deltas, w1, w2) are
// per-lane VGPRs loaded once; hot loop is pure v_add + ds_read2 + max/min — no s_load,
// no SALU, no lgkm coupling. Channel stride 245 (mod 32 = 21, coprime) spreads the
// random per-lane gathers across all 32 banks. Lane accumulates its channel's 32-px
// row in regs (static idx) and stores 128 B contiguous via 8x dwordx4.

#define IN_C  64
#define OUT_C 128
#define HH    64
#define WW    64
#define TH    4              // tile rows
#define TW    32             // tile cols
#define LR    (TH + 2)       // 6 rows incl. halo
#define LCV   (TW + 2)       // 34 valid cols incl. halo
#define LC    40             // padded row stride (dwords)
#define CHS   245            // channel stride: 245 % 32 = 21, gcd(21,32)=1 -> banks spread
#define NTHR  512

__global__ __launch_bounds__(NTHR, 4)
void minimax_conv_kernel(const float* __restrict__ x,
                         const float* __restrict__ w1,
                         const float* __restrict__ w2,
                         const int*   __restrict__ conn,
                         float*       __restrict__ out) {
    __shared__ float xs[IN_C * CHS];   // 64*245*4 = 62720 B

    const int tid  = threadIdx.x;
    const int wt   = blockIdx.x;   // 0..1   (W tiles)
    const int ht   = blockIdx.y;   // 0..15  (H tiles)
    const int b    = blockIdx.z;   // 0..15  (batch)
    const int h0   = ht * TH;
    const int w0   = wt * TW;

    const int lane = tid & 63;
    const int wid  = __builtin_amdgcn_readfirstlane(tid >> 6);  // 0..7
    const int chg  = wid & 1;      // channel half
    const int r    = wid >> 1;     // tile row 0..3
    const int o    = chg * 64 + lane;   // this lane's output channel

    // ---- per-lane channel constants (loaded once, live in VGPRs) ----
    int   dlt[9]; float w1v[9]; float w2v[3];
    #pragma unroll
    for (int t = 0; t < 9; ++t) {
        const int idx = conn[o * 9 + t];    // 0..575 = c*9 + kh*3 + kw
        const int c   = idx / 9;
        const int k   = idx - 9 * c;
        const int kh  = k / 3;
        const int kw  = k - 3 * kh;
        dlt[t] = c * CHS + kh * LC + kw;
        w1v[t] = w1[o * 9 + t];
    }
    #pragma unroll
    for (int p = 0; p < 3; ++p) w2v[p] = w2[o * 3 + p];

    // ---- stage x tile (all 64 channels, replicate-clamped halo) ----
    const float* xb = x + (size_t)b * IN_C * HH * WW;
    for (int i = tid; i < IN_C * LR * LCV; i += NTHR) {
        int c  = i / (LR * LCV);
        int rm = i - c * (LR * LCV);
        int rr = rm / LCV;
        int cc = rm - rr * LCV;
        int gh = h0 + rr - 1; gh = gh < 0 ? 0 : (gh > HH - 1 ? HH - 1 : gh);
        int gw = w0 + cc - 1; gw = gw < 0 ? 0 : (gw > WW - 1 ? WW - 1 : gw);
        xs[c * CHS + rr * LC + cc] = xb[(c * HH + gh) * WW + gw];
    }
    __syncthreads();

    // ---- compute: lane's channel over its row's 32 pixels (16 pairs c, c+16) ----
    const int base = r * LC;   // pixel (r, col): tap addr = base + col + dlt[t]
    float vout[32];            // full output row, statically indexed (full unroll)

    #pragma unroll
    for (int c0 = 0; c0 < 16; ++c0) {
        float a[9][2];
        #pragma unroll
        for (int t = 0; t < 9; ++t) {
            const int ad = base + c0 + dlt[t];
            a[t][0] = xs[ad];        // pair -> ds_read2_b32 offset0:0 offset1:16
            a[t][1] = xs[ad + 16];
        }
        #pragma unroll
        for (int px = 0; px < 2; ++px) {
            float mi = 0.0f;
            #pragma unroll
            for (int p = 0; p < 3; ++p) {
                float ma = a[p * 3 + 0][px] - w1v[p * 3 + 0];
                ma = fmaxf(ma, a[p * 3 + 1][px] - w1v[p * 3 + 1]);
                ma = fmaxf(ma, a[p * 3 + 2][px] - w1v[p * 3 + 2]);
                const float t2 = ma - w2v[p];
                mi = (p == 0) ? t2 : fminf(mi, t2);
            }
            vout[c0 + px * 16] = mi;
        }
    }

    // ---- store: 32 contiguous floats (128 B) per lane, 8x dwordx4 ----
    float* op = out + (((size_t)b * OUT_C + o) * HH + (h0 + r)) * WW + w0;
    #pragma unroll
    for (int q = 0; q < 8; ++q) {
        *reinterpret_cast<float4*>(op + q * 4) =
            make_float4(vout[4 * q], vout[4 * q + 1], vout[4 * q + 2], vout[4 * q + 3]);
    }
}

extern "C" void kernel_launch(void* const* d_in, const int* in_sizes, int n_in,
                              void* d_out, int out_size, void* d_ws, size_t ws_size,
                              hipStream_t stream) {
    const float* x    = (const float*)d_in[0];
    const float* w1   = (const float*)d_in[1];
    const float* w2   = (const float*)d_in[2];
    const int*   conn = (const int*)d_in[3];
    float*       out  = (float*)d_out;

    dim3 grid(WW / TW, HH / TH, 16);   // 2 x 16 x 16 = 512 blocks
    minimax_conv_kernel<<<grid, NTHR, 0, stream>>>(x, w1, w2, conn, out);
}